// Round 11
// baseline (150.791 us; speedup 1.0000x reference)
//
#include <hip/hip_runtime.h>
#include <hip/hip_bf16.h>
#include <math.h>

// Problem constants: B=4, S=512, N=8 sensors, D=256, H=8 heads, hd=32, BN=B*N=32
#define B_   4
#define S_   512
#define N_   8
#define D_   256
#define H_   8
#define HD_  32
#define BN_  32
#define MTOT (BN_ * S_)   // 16384 rows in the folded (BN,S) space

typedef __attribute__((ext_vector_type(8))) short short8;    // 8 bf16 = 4 VGPRs (MFMA A/B frag)
typedef __attribute__((ext_vector_type(4))) short short4v;   // 4 bf16 = 8 B
typedef __attribute__((ext_vector_type(4))) float floatx4;   // MFMA C/D frag / fp32 vec IO

// exp2-domain score scale: 1/sqrt(32) * log2(e), folded into the Q projection
#define QSCALE 0.25503468f

__device__ __forceinline__ unsigned short f2bf(float f) {
    union { float f; unsigned u; } c; c.f = f;
    unsigned lsb = (c.u >> 16) & 1u;
    c.u += 0x7fffu + lsb;          // round-to-nearest-even
    return (unsigned short)(c.u >> 16);
}
// cheap round-half-up bf16 pack (p >= 0 only; bias 2^-10 ulp, fine at 9.5e-2 thr)
__device__ __forceinline__ unsigned short f2bf_ru(float f) {
    union { float f; unsigned u; } c; c.f = f;
    return (unsigned short)((c.u + 0x8000u) >> 16);
}
__device__ __forceinline__ float fexp2(float x) {    // v_exp_f32 is native exp2
    float r; asm("v_exp_f32 %0, %1" : "=v"(r) : "v"(x)); return r;
}
// async global->LDS, 16 B per lane; LDS dest = wave-uniform base + lane*16 [m97/m104]
__device__ __forceinline__ void gload_lds16(const void* g, void* l) {
    __builtin_amdgcn_global_load_lds(
        (const __attribute__((address_space(1))) unsigned int*)g,
        (__attribute__((address_space(3))) unsigned int*)l, 16, 0, 0);
}

// ---------------------------------------------------------------------------
// Kernel 1: blocks 0..4095: x (B,S,N,D) fp32 + PE -> xpos (BN,S,D) bf16
//           blocks 4096..5119: round [Wq|Wk|Wv|Wo] fp32 -> bf16
// ---------------------------------------------------------------------------
__global__ __launch_bounds__(256) void prep_kernel(const float* __restrict__ x,
                                                   const float* __restrict__ Wq,
                                                   const float* __restrict__ Wk,
                                                   const float* __restrict__ Wv,
                                                   const float* __restrict__ Wo,
                                                   unsigned short* __restrict__ xpos,
                                                   unsigned short* __restrict__ wdst) {
    int bid = blockIdx.x;
    if (bid < 4096) {
        int idx4 = bid * 256 + threadIdx.x;            // over BN*S*D/4
        int d0 = (idx4 << 2) & (D_ - 1);
        int s  = (idx4 >> 6) & (S_ - 1);
        int bn = idx4 >> 15;
        int b = bn >> 3, n = bn & 7;
        floatx4 xv = *(const floatx4*)(x + ((((size_t)b * S_ + s) * N_ + n) << 8) + d0);
        const float cfreq = -9.210340371976184f / 256.0f;   // -ln(10000)/D
        float f0 = __expf((float)d0 * cfreq);
        float f1 = __expf((float)(d0 + 2) * cfreq);
        float a0 = (float)s * f0, a1 = (float)s * f1;
        short4v o;
        o[0] = (short)f2bf(xv[0] + __sinf(a0));
        o[1] = (short)f2bf(xv[1] + __cosf(a0));
        o[2] = (short)f2bf(xv[2] + __sinf(a1));
        o[3] = (short)f2bf(xv[3] + __cosf(a1));
        *(short4v*)(xpos + ((size_t)idx4 << 2)) = o;
    } else {
        int idx = (bid - 4096) * 256 + threadIdx.x;    // 0 .. 262143
        int which = idx >> 16, off = idx & 65535;
        const float* W = (which == 0) ? Wq : (which == 1) ? Wk : (which == 2) ? Wv : Wo;
        wdst[idx] = f2bf(W[off]);
    }
}

// ---------------------------------------------------------------------------
// Kernel 2: QKV GEMM, grid (128, 3): blockIdx.y = sel (0=Q,1=K,2=V).
// Block tile 128m x 256n; 4 waves, wave tile 64m x 128n (4x8 MFMA tiles,
// 128 acc VGPRs; __launch_bounds__(256,2) caps at 256 VGPR).
// A-strip (128x256 bf16 = 64 KB) staged ONCE per block into LDS via
// global_load_lds width=16 in lane-linear chunk layout:
//   Alds[(mt*8+kk)*512 + lane*8] = A[m_b + mt*16 + (lane&15)][kk*32+(lane>>4)*8]
// -> in-loop A reads are conflict-free ds_read_b128; A/W global traffic
// halves vs the (128,6) grid. W frags stay direct-global (L1/L2-hot).
// Outputs: Qh[bnh*512+s][32] (pre-scaled), Kh same, Vt[(bn*256+c)*512+s].
// ---------------------------------------------------------------------------
__global__ __launch_bounds__(256, 2) void gemm_qkv_kernel(const unsigned short* __restrict__ A,
                                                          const unsigned short* __restrict__ W,
                                                          const float* __restrict__ bq,
                                                          const float* __restrict__ bk,
                                                          const float* __restrict__ bv,
                                                          unsigned short* __restrict__ Qh,
                                                          unsigned short* __restrict__ Kh,
                                                          unsigned short* __restrict__ Vt) {
    __shared__ __align__(16) unsigned short Alds[32768];   // 64 KB
    int wv = threadIdx.x >> 6, lane = threadIdx.x & 63;
    int col = lane & 15, quad = lane >> 4;
    int m_b = blockIdx.x * 128;
    int sel = blockIdx.y;                       // 0=Q, 1=K, 2=V (block-uniform)
    int m_w = (wv >> 1) * 64;                   // wave m-offset within block
    int n_l = (wv & 1) * 128;                   // wave n-offset within 256-col output

    // ---- stage A strip: 64 chunks of 1 KB; wave wv stages chunks wv*16..+16
    for (int c = wv * 16; c < wv * 16 + 16; ++c) {
        int mt = c >> 3, kk = c & 7;
        const unsigned short* gp = A + (size_t)(m_b + mt * 16 + col) * 256 + kk * 32 + quad * 8;
        gload_lds16(gp, &Alds[c << 9]);         // uniform LDS base; HW adds lane*16B
    }
    __syncthreads();                             // drains vmcnt for global_load_lds

    const short8* Bp = (const short8*)(W + ((size_t)(sel * 256 + n_l + col)) * 256 + quad * 8);

    floatx4 acc[4][8] = {};
#pragma unroll
    for (int kk = 0; kk < 8; ++kk) {
        short8 a[4], b[8];
#pragma unroll
        for (int t = 0; t < 4; ++t)
            a[t] = *(const short8*)&Alds[((((m_w >> 4) + t) << 3) + kk) << 9 | (lane << 3)];
#pragma unroll
        for (int t = 0; t < 8; ++t)
            b[t] = Bp[t * 512 + kk * 4];
#pragma unroll
        for (int mt = 0; mt < 4; ++mt)
#pragma unroll
            for (int nt = 0; nt < 8; ++nt)
                acc[mt][nt] = __builtin_amdgcn_mfma_f32_16x16x32_bf16(a[mt], b[nt], acc[mt][nt], 0, 0, 0);
    }

    const float* bias = (sel == 0) ? bq : (sel == 1) ? bk : bv;
#pragma unroll
    for (int nt = 0; nt < 8; ++nt) {
        int c = n_l + nt * 16 + col;            // 0..255 output col
        float bv_ = bias[c];
#pragma unroll
        for (int mt = 0; mt < 4; ++mt) {
            int m0 = m_b + m_w + mt * 16 + quad * 4;
            int bn = m0 >> 9, s0 = m0 & (S_ - 1);
            if (sel == 2) {
                short4v pack;
#pragma unroll
                for (int r = 0; r < 4; ++r) pack[r] = (short)f2bf(acc[mt][nt][r] + bv_);
                *(short4v*)(Vt + (((size_t)((bn << 8) + c)) << 9) + s0) = pack;
            } else {
                int h2 = c >> 5, dl = c & 31;
                unsigned short* dst = ((sel == 0) ? Qh : Kh)
                    + ((((size_t)(bn * 8 + h2)) * 512 + s0) << 5) + dl;
                if (sel == 0) {
#pragma unroll
                    for (int r = 0; r < 4; ++r)
                        dst[r << 5] = f2bf((acc[mt][nt][r] + bv_) * QSCALE);
                } else {
#pragma unroll
                    for (int r = 0; r < 4; ++r)
                        dst[r << 5] = f2bf(acc[mt][nt][r] + bv_);
                }
            }
        }
    }
}

// ---------------------------------------------------------------------------
// Kernel 3: LDS-resident flash attention (R10 structure, unchanged).
// ---------------------------------------------------------------------------
__global__ __launch_bounds__(1024) void fattn_kernel(const unsigned short* __restrict__ Qh,
                                                     const unsigned short* __restrict__ Kh,
                                                     const unsigned short* __restrict__ Vt,
                                                     unsigned short* __restrict__ O) {
    __shared__ unsigned short Klds[16384];        // 32 KB
    __shared__ unsigned short Vlds[16384];        // 32 KB
    __shared__ unsigned short Plds[16][512];      // 16 KB   (total 80 KB)

    int t = threadIdx.x;
    int bnh = blockIdx.x;                  // bn*8 + h
    int bn = bnh >> 3, h = bnh & 7;
    int wv = t >> 6, lane = t & 63;
    int col = lane & 15, quad = lane >> 4;
    unsigned short* P = &Plds[wv][0];
    int qts[2] = { wv, 31 - wv };          // balanced causal pair (~17 iters total)

    short8 qf[2];
#pragma unroll
    for (int ui = 0; ui < 2; ++ui)
        qf[ui] = *(const short8*)(Qh + (((size_t)(bnh * S_ + qts[ui] * 16 + col)) << 5) + quad * 8);

    const unsigned short* Ksrc = Kh + ((size_t)bnh << 14);   // 512 x 32
    const unsigned short* Vsrc = Vt + ((size_t)bnh << 14);   // 32 x 512
#pragma unroll
    for (int i = 0; i < 2; ++i) {
        int g = t + i * 1024;              // 0..2047 chunks
        int kt = g >> 7, r = g & 127;
        int half = r >> 6, lin = r & 63;
        int c = lin & 15, q = lin >> 4;
        *(short8*)&Klds[(kt << 10) + (half << 9) + (lin << 3)] =
            *(const short8*)(Ksrc + ((kt * 32 + half * 16 + c) << 5) + (q << 3));
        *(short8*)&Vlds[(kt << 10) + (half << 9) + (lin << 3)] =
            *(const short8*)(Vsrc + (((half << 4) + c) << 9) + (kt << 5) + (q << 3));
    }
    __syncthreads();

#pragma unroll
    for (int ui = 0; ui < 2; ++ui) {
        int q0 = qts[ui] * 16;
        short8 qfrag = qf[ui];
        float l = 0.f;
        floatx4 o0 = {0.f, 0.f, 0.f, 0.f};   // O^T d=0..15 (row=d=quad*4+r, col=q)
        floatx4 o1 = {0.f, 0.f, 0.f, 0.f};   // O^T d=16..31
        int lastk = q0 >> 5;

        for (int kt = 0; kt <= lastk; ++kt) {
            int k0 = kt * 32;
            int tb = kt << 10;
            short8 kf0 = *(const short8*)&Klds[tb + (lane << 3)];
            short8 kf1 = *(const short8*)&Klds[tb + 512 + (lane << 3)];
            floatx4 z = {0.f, 0.f, 0.f, 0.f};
            floatx4 st0 = __builtin_amdgcn_mfma_f32_16x16x32_bf16(kf0, qfrag, z, 0, 0, 0);
            floatx4 st1 = __builtin_amdgcn_mfma_f32_16x16x32_bf16(kf1, qfrag, z, 0, 0, 0);

            if (kt == lastk) {             // causal mask, wave-uniform branch
                int qg = q0 + col;
#pragma unroll
                for (int r = 0; r < 4; ++r) {
                    if (k0 + quad * 4 + r > qg)      st0[r] = -1e30f;
                    if (k0 + 16 + quad * 4 + r > qg) st1[r] = -1e30f;
                }
            }

            float p[8]; float ts = 0.f;
#pragma unroll
            for (int r = 0; r < 4; ++r) {
                p[r]     = fexp2(st0[r]);
                p[4 + r] = fexp2(st1[r]);
                ts += p[r] + p[4 + r];
            }
            ts += __shfl_xor(ts, 16);
            ts += __shfl_xor(ts, 32);
            l += ts;

            short4v pk0, pk1;
#pragma unroll
            for (int r = 0; r < 4; ++r) {
                pk0[r] = (short)f2bf_ru(p[r]);
                pk1[r] = (short)f2bf_ru(p[4 + r]);
            }
            int qh_ = quad >> 1, ql_ = (quad & 1) << 2;
            *(short4v*)&P[(((qh_) * 16 + col) << 3) + ql_]     = pk0;
            *(short4v*)&P[(((2 + qh_) * 16 + col) << 3) + ql_] = pk1;
            short8 pfrag = *(const short8*)&P[lane << 3];   // same-wave DS order

            short8 vf0 = *(const short8*)&Vlds[tb + (lane << 3)];
            short8 vf1 = *(const short8*)&Vlds[tb + 512 + (lane << 3)];
            o0 = __builtin_amdgcn_mfma_f32_16x16x32_bf16(vf0, pfrag, o0, 0, 0, 0);
            o1 = __builtin_amdgcn_mfma_f32_16x16x32_bf16(vf1, pfrag, o1, 0, 0, 0);
        }

        float inv = 1.0f / l;
        unsigned short* Op = O + (((size_t)(bn * S_ + q0 + col)) << 8) + h * HD_;
        short4v s0v, s1v;
#pragma unroll
        for (int r = 0; r < 4; ++r) {
            s0v[r] = (short)f2bf(o0[r] * inv);
            s1v[r] = (short)f2bf(o1[r] * inv);
        }
        *(short4v*)(Op + quad * 4)      = s0v;
        *(short4v*)(Op + 16 + quad * 4) = s1v;
    }
}

// ---------------------------------------------------------------------------
// Kernel 4: FUSED output projection + bias + residual + LayerNorm.
// 256 blocks x 64 rows; 4 waves, wave w covers cols [w*64, w*64+64).
// Output now bounced through LDS (rows padded to 260 floats) so final
// stores are one contiguous 1 KB global_store_dwordx4 per wave-instruction.
// ---------------------------------------------------------------------------
#define YSTR 260
__global__ __launch_bounds__(256) void gemm_o_ln_kernel(const unsigned short* __restrict__ A,
                                                        const unsigned short* __restrict__ W,
                                                        const float* __restrict__ bo,
                                                        const float* __restrict__ x,
                                                        const float* __restrict__ gamma,
                                                        const float* __restrict__ beta,
                                                        float* __restrict__ out) {
    __shared__ __align__(16) float Yl[64 * YSTR];   // 65 KB
    __shared__ float lsum[4][64];
    __shared__ float lss[4][64];
    __shared__ float lmu[64];
    __shared__ float lrs[64];

    int wv = threadIdx.x >> 6, lane = threadIdx.x & 63;
    int col = lane & 15, quad = lane >> 4;
    int m_b = blockIdx.x * 64;                 // 64 rows per block, bn-uniform
    int n_w = wv * 64;

    const short8* Ap = (const short8*)(A + (size_t)(m_b + col) * 256 + quad * 8);
    const short8* Bp = (const short8*)(W + (size_t)(n_w + col) * 256 + quad * 8);

    floatx4 acc[4][4] = {};
#pragma unroll
    for (int kk = 0; kk < 8; ++kk) {
        short8 a[4], b[4];
#pragma unroll
        for (int t = 0; t < 4; ++t) {
            a[t] = Ap[t * 512 + kk * 4];
            b[t] = Bp[t * 512 + kk * 4];
        }
#pragma unroll
        for (int mt = 0; mt < 4; ++mt)
#pragma unroll
            for (int nt = 0; nt < 4; ++nt)
                acc[mt][nt] = __builtin_amdgcn_mfma_f32_16x16x32_bf16(a[mt], b[nt], acc[mt][nt], 0, 0, 0);
    }

    int bn = m_b >> 9, s0 = m_b & (S_ - 1);
    int b_ = bn >> 3, n_ = bn & 7;
    const float* xrow = x + ((((size_t)b_ * S_ + s0) * N_ + n_) << 8);   // row stride 2048 floats
    float* orow = out + ((((size_t)b_ * S_ + s0) * N_ + n_) << 8);

    float psum[4][4] = {};   // [mt][r]
    float pss[4][4]  = {};
#pragma unroll
    for (int nt = 0; nt < 4; ++nt) {
        int c = n_w + nt * 16 + col;
        float bv_ = bo[c];
#pragma unroll
        for (int mt = 0; mt < 4; ++mt) {
            int sl = mt * 16 + quad * 4;       // local row (s offset within block)
#pragma unroll
            for (int r = 0; r < 4; ++r) {
                float y = acc[mt][nt][r] + bv_ + xrow[(size_t)(sl + r) * 2048 + c];
                acc[mt][nt][r] = y;
                psum[mt][r] += y;
                pss[mt][r]  += y * y;
            }
        }
    }
#pragma unroll
    for (int off = 8; off >= 1; off >>= 1) {
#pragma unroll
        for (int mt = 0; mt < 4; ++mt)
#pragma unroll
            for (int r = 0; r < 4; ++r) {
                psum[mt][r] += __shfl_xor(psum[mt][r], off);
                pss[mt][r]  += __shfl_xor(pss[mt][r], off);
            }
    }
    if (col == 0) {
#pragma unroll
        for (int mt = 0; mt < 4; ++mt)
#pragma unroll
            for (int r = 0; r < 4; ++r) {
                lsum[wv][mt * 16 + quad * 4 + r] = psum[mt][r];
                lss[wv][mt * 16 + quad * 4 + r]  = pss[mt][r];
            }
    }
    __syncthreads();
    if (threadIdx.x < 64) {
        int row = threadIdx.x;
        float s  = lsum[0][row] + lsum[1][row] + lsum[2][row] + lsum[3][row];
        float ss = lss[0][row] + lss[1][row] + lss[2][row] + lss[3][row];
        float mu = s * (1.0f / 256.0f);
        float var = ss * (1.0f / 256.0f) - mu * mu;   // biased var (jnp.var)
        lmu[row] = mu;
        lrs[row] = rsqrtf(var + 1e-5f);
    }
    __syncthreads();

    // normalize into LDS bounce buffer
#pragma unroll
    for (int nt = 0; nt < 4; ++nt) {
        int c = n_w + nt * 16 + col;
        float g  = gamma[c];
        float be = beta[c];
#pragma unroll
        for (int mt = 0; mt < 4; ++mt) {
            int sl = mt * 16 + quad * 4;
#pragma unroll
            for (int r = 0; r < 4; ++r)
                Yl[(sl + r) * YSTR + c] = (acc[mt][nt][r] - lmu[sl + r]) * lrs[sl + r] * g + be;
        }
    }
    __syncthreads();

    // coalesced store: each instr = one full 256-float row (1 KB contiguous)
#pragma unroll
    for (int i = 0; i < 16; ++i) {
        int linear = i * 1024 + threadIdx.x * 4;      // over 16384 floats
        int row = linear >> 8, c4 = linear & 255;
        floatx4 v = *(const floatx4*)&Yl[row * YSTR + c4];
        *(floatx4*)&orow[(size_t)row * 2048 + c4] = v;
    }
}

// ---------------------------------------------------------------------------
extern "C" void kernel_launch(void* const* d_in, const int* in_sizes, int n_in,
                              void* d_out, int out_size, void* d_ws, size_t ws_size,
                              hipStream_t stream) {
    const float* x     = (const float*)d_in[0];
    const float* Wq    = (const float*)d_in[1];
    const float* Wk    = (const float*)d_in[2];
    const float* Wv    = (const float*)d_in[3];
    const float* Wo    = (const float*)d_in[4];
    const float* bq    = (const float*)d_in[5];
    const float* bk    = (const float*)d_in[6];
    const float* bv    = (const float*)d_in[7];
    const float* bo    = (const float*)d_in[8];
    const float* gamma = (const float*)d_in[9];
    const float* beta  = (const float*)d_in[10];

    // Workspace layout (16B-aligned), total 40.5 MB:
    //   [0   .. 8MB )  xpos bf16 (BN,S,D)
    //   [8MB .. 16MB)  Qh   bf16 head-major [bnh*512+s][32] (pre-scaled)
    //   [16MB.. 24MB)  Kh   bf16 head-major [bnh*512+s][32]
    //   [24MB.. 32MB)  Vt   bf16 transposed [(bn*256+c)][512]
    //   [32MB.. 40MB)  Ab   bf16 (attn out, row-major (BN,S,D))
    //   [40MB.. +512KB) Wbf bf16 [Wq|Wk|Wv|Wo]
    char* w = (char*)d_ws;
    const size_t SZ = (size_t)MTOT * D_ * 2;   // 8 MB
    unsigned short* xpos = (unsigned short*)(w);
    unsigned short* Qh   = (unsigned short*)(w + SZ);
    unsigned short* Kh   = (unsigned short*)(w + 2 * SZ);
    unsigned short* Vt   = (unsigned short*)(w + 3 * SZ);
    unsigned short* Ab   = (unsigned short*)(w + 4 * SZ);
    unsigned short* Wbf  = (unsigned short*)(w + 5 * SZ);

    prep_kernel<<<5120, 256, 0, stream>>>(x, Wq, Wk, Wv, Wo, xpos, Wbf);
    gemm_qkv_kernel<<<dim3(128, 3), 256, 0, stream>>>(xpos, Wbf, bq, bk, bv, Qh, Kh, Vt);
    fattn_kernel<<<256, 1024, 0, stream>>>(Qh, Kh, Vt, Ab);
    gemm_o_ln_kernel<<<256, 256, 0, stream>>>(Ab, Wbf + 3 * 65536, bo, x, gamma, beta, (float*)d_out);
}

// Round 12
// 147.768 us; speedup vs baseline: 1.0205x; 1.0205x over previous
//
#include <hip/hip_runtime.h>
#include <hip/hip_bf16.h>
#include <math.h>

// Problem constants: B=4, S=512, N=8 sensors, D=256, H=8 heads, hd=32, BN=B*N=32
#define B_   4
#define S_   512
#define N_   8
#define D_   256
#define H_   8
#define HD_  32
#define BN_  32
#define MTOT (BN_ * S_)   // 16384 rows in the folded (BN,S) space

typedef __attribute__((ext_vector_type(8))) short short8;    // 8 bf16 = 4 VGPRs (MFMA A/B frag)
typedef __attribute__((ext_vector_type(4))) short short4v;   // 4 bf16 = 8 B
typedef __attribute__((ext_vector_type(4))) float floatx4;   // MFMA C/D frag / fp32 vec IO

// exp2-domain score scale: 1/sqrt(32) * log2(e), folded into the Q projection
#define QSCALE 0.25503468f

__device__ __forceinline__ unsigned short f2bf(float f) {
    union { float f; unsigned u; } c; c.f = f;
    unsigned lsb = (c.u >> 16) & 1u;
    c.u += 0x7fffu + lsb;          // round-to-nearest-even
    return (unsigned short)(c.u >> 16);
}
// cheap round-half-up bf16 pack (p >= 0 only; bias 2^-10 ulp, fine at 9.5e-2 thr)
__device__ __forceinline__ unsigned short f2bf_ru(float f) {
    union { float f; unsigned u; } c; c.f = f;
    return (unsigned short)((c.u + 0x8000u) >> 16);
}
__device__ __forceinline__ float fexp2(float x) {    // v_exp_f32 is native exp2
    float r; asm("v_exp_f32 %0, %1" : "=v"(r) : "v"(x)); return r;
}

// ---------------------------------------------------------------------------
// Kernel 1: blocks 0..4095: x (B,S,N,D) fp32 + PE -> xpos (BN,S,D) bf16
//           blocks 4096..5119: round [Wq|Wk|Wv|Wo] fp32 -> bf16
// ---------------------------------------------------------------------------
__global__ __launch_bounds__(256) void prep_kernel(const float* __restrict__ x,
                                                   const float* __restrict__ Wq,
                                                   const float* __restrict__ Wk,
                                                   const float* __restrict__ Wv,
                                                   const float* __restrict__ Wo,
                                                   unsigned short* __restrict__ xpos,
                                                   unsigned short* __restrict__ wdst) {
    int bid = blockIdx.x;
    if (bid < 4096) {
        int idx4 = bid * 256 + threadIdx.x;            // over BN*S*D/4
        int d0 = (idx4 << 2) & (D_ - 1);
        int s  = (idx4 >> 6) & (S_ - 1);
        int bn = idx4 >> 15;
        int b = bn >> 3, n = bn & 7;
        floatx4 xv = *(const floatx4*)(x + ((((size_t)b * S_ + s) * N_ + n) << 8) + d0);
        const float cfreq = -9.210340371976184f / 256.0f;   // -ln(10000)/D
        float f0 = __expf((float)d0 * cfreq);
        float f1 = __expf((float)(d0 + 2) * cfreq);
        float a0 = (float)s * f0, a1 = (float)s * f1;
        short4v o;
        o[0] = (short)f2bf(xv[0] + __sinf(a0));
        o[1] = (short)f2bf(xv[1] + __cosf(a0));
        o[2] = (short)f2bf(xv[2] + __sinf(a1));
        o[3] = (short)f2bf(xv[3] + __cosf(a1));
        *(short4v*)(xpos + ((size_t)idx4 << 2)) = o;
    } else {
        int idx = (bid - 4096) * 256 + threadIdx.x;    // 0 .. 262143
        int which = idx >> 16, off = idx & 65535;
        const float* W = (which == 0) ? Wq : (which == 1) ? Wk : (which == 2) ? Wv : Wo;
        wdst[idx] = f2bf(W[off]);
    }
}

// ---------------------------------------------------------------------------
// Kernel 2: fused QKV GEMM (R10 version — best measured). A(16384,256) @
// Wqkv(768,256)^T + bias. 128x128 block tile, 4 waves x 64x64. Head-major
// outputs: Qh[bnh*512+s][32] (pre-scaled), Kh same, Vt[(bn*256+c)*512+s].
// ---------------------------------------------------------------------------
__global__ __launch_bounds__(256) void gemm_qkv_kernel(const unsigned short* __restrict__ A,
                                                       const unsigned short* __restrict__ W,
                                                       const float* __restrict__ bq,
                                                       const float* __restrict__ bk,
                                                       const float* __restrict__ bv,
                                                       unsigned short* __restrict__ Qh,
                                                       unsigned short* __restrict__ Kh,
                                                       unsigned short* __restrict__ Vt) {
    int wv = threadIdx.x >> 6, lane = threadIdx.x & 63;
    int col = lane & 15, quad = lane >> 4;
    int m_w = blockIdx.x * 128 + (wv >> 1) * 64;
    int n_w = blockIdx.y * 128 + (wv & 1) * 64;

    const short8* Ap = (const short8*)(A + (size_t)(m_w + col) * 256 + quad * 8);
    const short8* Bp = (const short8*)(W + (size_t)(n_w + col) * 256 + quad * 8);

    floatx4 acc[4][4] = {};
#pragma unroll
    for (int kk = 0; kk < 8; ++kk) {
        short8 a[4], b[4];
#pragma unroll
        for (int t = 0; t < 4; ++t) {
            a[t] = Ap[t * 512 + kk * 4];
            b[t] = Bp[t * 512 + kk * 4];
        }
#pragma unroll
        for (int mt = 0; mt < 4; ++mt)
#pragma unroll
            for (int nt = 0; nt < 4; ++nt)
                acc[mt][nt] = __builtin_amdgcn_mfma_f32_16x16x32_bf16(a[mt], b[nt], acc[mt][nt], 0, 0, 0);
    }

    int sel = blockIdx.y >> 1;                     // 0=Q, 1=K, 2=V (uniform)
    const float* bias = (sel == 0) ? bq : (sel == 1) ? bk : bv;
#pragma unroll
    for (int nt = 0; nt < 4; ++nt) {
        int c = n_w + nt * 16 + col - sel * 256;   // 0..255 within output
        float bv_ = bias[c];
#pragma unroll
        for (int mt = 0; mt < 4; ++mt) {
            int m0 = m_w + mt * 16 + quad * 4;
            int bn = m0 >> 9, s0 = m0 & (S_ - 1);
            if (sel == 2) {
                short4v pack;
#pragma unroll
                for (int r = 0; r < 4; ++r) pack[r] = (short)f2bf(acc[mt][nt][r] + bv_);
                *(short4v*)(Vt + (((size_t)((bn << 8) + c)) << 9) + s0) = pack;
            } else {
                int h2 = c >> 5, dl = c & 31;
                unsigned short* dst = ((sel == 0) ? Qh : Kh)
                    + ((((size_t)(bn * 8 + h2)) * 512 + s0) << 5) + dl;
                if (sel == 0) {
#pragma unroll
                    for (int r = 0; r < 4; ++r)
                        dst[r << 5] = f2bf((acc[mt][nt][r] + bv_) * QSCALE);
                } else {
#pragma unroll
                    for (int r = 0; r < 4; ++r)
                        dst[r << 5] = f2bf(acc[mt][nt][r] + bv_);
                }
            }
        }
    }
}

// ---------------------------------------------------------------------------
// Kernel 3: LDS-resident flash attention (R10 structure, unchanged).
// ---------------------------------------------------------------------------
__global__ __launch_bounds__(1024) void fattn_kernel(const unsigned short* __restrict__ Qh,
                                                     const unsigned short* __restrict__ Kh,
                                                     const unsigned short* __restrict__ Vt,
                                                     unsigned short* __restrict__ O) {
    __shared__ unsigned short Klds[16384];        // 32 KB
    __shared__ unsigned short Vlds[16384];        // 32 KB
    __shared__ unsigned short Plds[16][512];      // 16 KB   (total 80 KB)

    int t = threadIdx.x;
    int bnh = blockIdx.x;                  // bn*8 + h
    int bn = bnh >> 3, h = bnh & 7;
    int wv = t >> 6, lane = t & 63;
    int col = lane & 15, quad = lane >> 4;
    unsigned short* P = &Plds[wv][0];
    int qts[2] = { wv, 31 - wv };          // balanced causal pair (~17 iters total)

    short8 qf[2];
#pragma unroll
    for (int ui = 0; ui < 2; ++ui)
        qf[ui] = *(const short8*)(Qh + (((size_t)(bnh * S_ + qts[ui] * 16 + col)) << 5) + quad * 8);

    const unsigned short* Ksrc = Kh + ((size_t)bnh << 14);   // 512 x 32
    const unsigned short* Vsrc = Vt + ((size_t)bnh << 14);   // 32 x 512
#pragma unroll
    for (int i = 0; i < 2; ++i) {
        int g = t + i * 1024;              // 0..2047 chunks
        int kt = g >> 7, r = g & 127;
        int half = r >> 6, lin = r & 63;
        int c = lin & 15, q = lin >> 4;
        *(short8*)&Klds[(kt << 10) + (half << 9) + (lin << 3)] =
            *(const short8*)(Ksrc + ((kt * 32 + half * 16 + c) << 5) + (q << 3));
        *(short8*)&Vlds[(kt << 10) + (half << 9) + (lin << 3)] =
            *(const short8*)(Vsrc + (((half << 4) + c) << 9) + (kt << 5) + (q << 3));
    }
    __syncthreads();

#pragma unroll
    for (int ui = 0; ui < 2; ++ui) {
        int q0 = qts[ui] * 16;
        short8 qfrag = qf[ui];
        float l = 0.f;
        floatx4 o0 = {0.f, 0.f, 0.f, 0.f};   // O^T d=0..15 (row=d=quad*4+r, col=q)
        floatx4 o1 = {0.f, 0.f, 0.f, 0.f};   // O^T d=16..31
        int lastk = q0 >> 5;

        for (int kt = 0; kt <= lastk; ++kt) {
            int k0 = kt * 32;
            int tb = kt << 10;
            short8 kf0 = *(const short8*)&Klds[tb + (lane << 3)];
            short8 kf1 = *(const short8*)&Klds[tb + 512 + (lane << 3)];
            floatx4 z = {0.f, 0.f, 0.f, 0.f};
            floatx4 st0 = __builtin_amdgcn_mfma_f32_16x16x32_bf16(kf0, qfrag, z, 0, 0, 0);
            floatx4 st1 = __builtin_amdgcn_mfma_f32_16x16x32_bf16(kf1, qfrag, z, 0, 0, 0);

            if (kt == lastk) {             // causal mask, wave-uniform branch
                int qg = q0 + col;
#pragma unroll
                for (int r = 0; r < 4; ++r) {
                    if (k0 + quad * 4 + r > qg)      st0[r] = -1e30f;
                    if (k0 + 16 + quad * 4 + r > qg) st1[r] = -1e30f;
                }
            }

            float p[8]; float ts = 0.f;
#pragma unroll
            for (int r = 0; r < 4; ++r) {
                p[r]     = fexp2(st0[r]);
                p[4 + r] = fexp2(st1[r]);
                ts += p[r] + p[4 + r];
            }
            ts += __shfl_xor(ts, 16);
            ts += __shfl_xor(ts, 32);
            l += ts;

            short4v pk0, pk1;
#pragma unroll
            for (int r = 0; r < 4; ++r) {
                pk0[r] = (short)f2bf_ru(p[r]);
                pk1[r] = (short)f2bf_ru(p[4 + r]);
            }
            int qh_ = quad >> 1, ql_ = (quad & 1) << 2;
            *(short4v*)&P[(((qh_) * 16 + col) << 3) + ql_]     = pk0;
            *(short4v*)&P[(((2 + qh_) * 16 + col) << 3) + ql_] = pk1;
            short8 pfrag = *(const short8*)&P[lane << 3];   // same-wave DS order

            short8 vf0 = *(const short8*)&Vlds[tb + (lane << 3)];
            short8 vf1 = *(const short8*)&Vlds[tb + 512 + (lane << 3)];
            o0 = __builtin_amdgcn_mfma_f32_16x16x32_bf16(vf0, pfrag, o0, 0, 0, 0);
            o1 = __builtin_amdgcn_mfma_f32_16x16x32_bf16(vf1, pfrag, o1, 0, 0, 0);
        }

        float inv = 1.0f / l;
        unsigned short* Op = O + (((size_t)(bn * S_ + q0 + col)) << 8) + h * HD_;
        short4v s0v, s1v;
#pragma unroll
        for (int r = 0; r < 4; ++r) {
            s0v[r] = (short)f2bf(o0[r] * inv);
            s1v[r] = (short)f2bf(o1[r] * inv);
        }
        *(short4v*)(Op + quad * 4)      = s0v;
        *(short4v*)(Op + 16 + quad * 4) = s1v;
    }
}

// ---------------------------------------------------------------------------
// Kernel 4: FUSED output projection + bias + residual + LayerNorm, v2.
// 256 blocks x 64 rows; 4 waves, wave w computes cols [w*64, w*64+64) (MFMA
// part identical to R10). Epilogue restructured into two passes:
//   P1: raw acc -> Yl LDS tile (YSTR=260 -> 2-way banks on both sides).
//   P2: wave w owns rows {w, 4+w, ...}: per row ONE coalesced 1 KB floatx4
//       load of x + LDS row read + bo add -> sum/ss via 12 shuffle-adds ->
//       normalize -> ONE coalesced 1 KB store. No scattered global access
//       remains in this kernel; cross-wave LDS stats reduce eliminated.
// ---------------------------------------------------------------------------
#define YSTR 260
__global__ __launch_bounds__(256) void gemm_o_ln_kernel(const unsigned short* __restrict__ A,
                                                        const unsigned short* __restrict__ W,
                                                        const float* __restrict__ bo,
                                                        const float* __restrict__ x,
                                                        const float* __restrict__ gamma,
                                                        const float* __restrict__ beta,
                                                        float* __restrict__ out) {
    __shared__ __align__(16) float Yl[64 * YSTR];   // 65 KB

    int wv = threadIdx.x >> 6, lane = threadIdx.x & 63;
    int col = lane & 15, quad = lane >> 4;
    int m_b = blockIdx.x * 64;                 // 64 rows per block, bn-uniform
    int n_w = wv * 64;

    const short8* Ap = (const short8*)(A + (size_t)(m_b + col) * 256 + quad * 8);
    const short8* Bp = (const short8*)(W + (size_t)(n_w + col) * 256 + quad * 8);

    floatx4 acc[4][4] = {};
#pragma unroll
    for (int kk = 0; kk < 8; ++kk) {
        short8 a[4], b[4];
#pragma unroll
        for (int t = 0; t < 4; ++t) {
            a[t] = Ap[t * 512 + kk * 4];
            b[t] = Bp[t * 512 + kk * 4];
        }
#pragma unroll
        for (int mt = 0; mt < 4; ++mt)
#pragma unroll
            for (int nt = 0; nt < 4; ++nt)
                acc[mt][nt] = __builtin_amdgcn_mfma_f32_16x16x32_bf16(a[mt], b[nt], acc[mt][nt], 0, 0, 0);
    }

    // P1: raw acc into LDS (frag-layout writes; YSTR=260 -> 2-way banks, free)
#pragma unroll
    for (int nt = 0; nt < 4; ++nt) {
        int c = n_w + nt * 16 + col;
#pragma unroll
        for (int mt = 0; mt < 4; ++mt) {
            int sl = mt * 16 + quad * 4;
#pragma unroll
            for (int r = 0; r < 4; ++r)
                Yl[(sl + r) * YSTR + c] = acc[mt][nt][r];
        }
    }
    __syncthreads();

    // P2: coalesced residual + LayerNorm, one full row per wave-iteration
    int bn = m_b >> 9, s0 = m_b & (S_ - 1);
    int b_ = bn >> 3, n_ = bn & 7;
    const float* xrow = x + ((((size_t)b_ * S_ + s0) * N_ + n_) << 8);   // row stride 2048 floats
    float* orow = out + ((((size_t)b_ * S_ + s0) * N_ + n_) << 8);

    floatx4 g4  = *(const floatx4*)(gamma + (lane << 2));
    floatx4 be4 = *(const floatx4*)(beta  + (lane << 2));
    floatx4 bo4 = *(const floatx4*)(bo    + (lane << 2));

#pragma unroll
    for (int i = 0; i < 16; ++i) {
        int row = i * 4 + wv;                  // local row 0..63
        floatx4 yv = *(const floatx4*)&Yl[row * YSTR + (lane << 2)];
        floatx4 xv = *(const floatx4*)&xrow[(size_t)row * 2048 + (lane << 2)];
        float s = 0.f, ss = 0.f;
#pragma unroll
        for (int j = 0; j < 4; ++j) {
            yv[j] += xv[j] + bo4[j];
            s  += yv[j];
            ss += yv[j] * yv[j];
        }
#pragma unroll
        for (int off = 1; off <= 32; off <<= 1) {
            s  += __shfl_xor(s, off);
            ss += __shfl_xor(ss, off);
        }
        float mu   = s * (1.0f / 256.0f);
        float var  = ss * (1.0f / 256.0f) - mu * mu;   // biased var (jnp.var)
        float rstd = rsqrtf(var + 1e-5f);
        floatx4 o;
#pragma unroll
        for (int j = 0; j < 4; ++j)
            o[j] = (yv[j] - mu) * rstd * g4[j] + be4[j];
        *(floatx4*)&orow[(size_t)row * 2048 + (lane << 2)] = o;
    }
}

// ---------------------------------------------------------------------------
extern "C" void kernel_launch(void* const* d_in, const int* in_sizes, int n_in,
                              void* d_out, int out_size, void* d_ws, size_t ws_size,
                              hipStream_t stream) {
    const float* x     = (const float*)d_in[0];
    const float* Wq    = (const float*)d_in[1];
    const float* Wk    = (const float*)d_in[2];
    const float* Wv    = (const float*)d_in[3];
    const float* Wo    = (const float*)d_in[4];
    const float* bq    = (const float*)d_in[5];
    const float* bk    = (const float*)d_in[6];
    const float* bv    = (const float*)d_in[7];
    const float* bo    = (const float*)d_in[8];
    const float* gamma = (const float*)d_in[9];
    const float* beta  = (const float*)d_in[10];

    // Workspace layout (16B-aligned), total 40.5 MB:
    //   [0   .. 8MB )  xpos bf16 (BN,S,D)
    //   [8MB .. 16MB)  Qh   bf16 head-major [bnh*512+s][32] (pre-scaled)
    //   [16MB.. 24MB)  Kh   bf16 head-major [bnh*512+s][32]
    //   [24MB.. 32MB)  Vt   bf16 transposed [(bn*256+c)][512]
    //   [32MB.. 40MB)  Ab   bf16 (attn out, row-major (BN,S,D))
    //   [40MB.. +512KB) Wbf bf16 [Wq|Wk|Wv|Wo]
    char* w = (char*)d_ws;
    const size_t SZ = (size_t)MTOT * D_ * 2;   // 8 MB
    unsigned short* xpos = (unsigned short*)(w);
    unsigned short* Qh   = (unsigned short*)(w + SZ);
    unsigned short* Kh   = (unsigned short*)(w + 2 * SZ);
    unsigned short* Vt   = (unsigned short*)(w + 3 * SZ);
    unsigned short* Ab   = (unsigned short*)(w + 4 * SZ);
    unsigned short* Wbf  = (unsigned short*)(w + 5 * SZ);

    prep_kernel<<<5120, 256, 0, stream>>>(x, Wq, Wk, Wv, Wo, xpos, Wbf);
    gemm_qkv_kernel<<<dim3(128, 6), 256, 0, stream>>>(xpos, Wbf, bq, bk, bv, Qh, Kh, Vt);
    fattn_kernel<<<256, 1024, 0, stream>>>(Qh, Kh, Vt, Ab);
    gemm_o_ln_kernel<<<256, 256, 0, stream>>>(Ab, Wbf + 3 * 65536, bo, x, gamma, beta, (float*)d_out);
}